// Round 5
// baseline (845.606 us; speedup 1.0000x reference)
//
#include <hip/hip_runtime.h>
#include <math.h>

#define N_NODES 50000
#define N_EDGES 800000
#define ENC 64
#define ROUNDS 3
#define NEG_SLOPE 0.2f

typedef unsigned int u32;

__device__ __forceinline__ float lrelu(float m) {
  return m > 0.f ? m : NEG_SLOPE * m;
}

// ---------------- CSR build ----------------
__global__ void k_hist(const int* __restrict__ dst, int* __restrict__ deg) {
  int i = blockIdx.x * blockDim.x + threadIdx.x;
  int stride = gridDim.x * blockDim.x;
  for (; i < N_EDGES; i += stride) atomicAdd(&deg[dst[i]], 1);
}

#define SCAN_BLOCKS ((N_NODES + 255) / 256)  // 196

__global__ void __launch_bounds__(256) k_red(const int* __restrict__ deg,
                                             int* __restrict__ part) {
  __shared__ int sm[256];
  int bi = blockIdx.x, t = threadIdx.x;
  int i = bi * 256 + t;
  sm[t] = (i < N_NODES) ? deg[i] : 0;
  __syncthreads();
  for (int off = 128; off > 0; off >>= 1) {
    if (t < off) sm[t] += sm[t + off];
    __syncthreads();
  }
  if (t == 0) part[bi] = sm[0];
}

__global__ void __launch_bounds__(256) k_scanp(int* __restrict__ part) {
  __shared__ int sm[256];
  int t = threadIdx.x;
  int v = (t < SCAN_BLOCKS) ? part[t] : 0;
  sm[t] = v;
  __syncthreads();
  for (int off = 1; off < 256; off <<= 1) {
    int u = (t >= off) ? sm[t - off] : 0;
    __syncthreads();
    sm[t] += u;
    __syncthreads();
  }
  if (t < SCAN_BLOCKS) part[t] = sm[t] - v;  // exclusive
}

// degcur: degrees on entry, scatter cursors (= row_start) on exit.
__global__ void __launch_bounds__(256) k_csr(int* __restrict__ degcur,
                                             const int* __restrict__ part,
                                             int* __restrict__ row_start) {
  __shared__ int sm[256];
  int bi = blockIdx.x, t = threadIdx.x;
  int i = bi * 256 + t;
  int v = (i < N_NODES) ? degcur[i] : 0;
  sm[t] = v;
  __syncthreads();
  for (int off = 1; off < 256; off <<= 1) {
    int u = (t >= off) ? sm[t - off] : 0;
    __syncthreads();
    sm[t] += u;
    __syncthreads();
  }
  int excl = sm[t] - v + part[bi];
  if (i < N_NODES) {
    row_start[i] = excl;
    degcur[i] = excl;
    if (i == N_NODES - 1) row_start[N_NODES] = excl + v;
  }
}

// scatter edges into CSR order; also permute edge_attr so the fused kernel
// reads it coalesced (ea_perm[pos] = ea[e]).
__global__ void k_scatter(const int* __restrict__ src, const int* __restrict__ dst,
                          const float* __restrict__ ea, int* __restrict__ cursor,
                          int* __restrict__ srcs, float* __restrict__ ea_perm) {
  int i = blockIdx.x * blockDim.x + threadIdx.x;
  int stride = gridDim.x * blockDim.x;
  for (; i < N_EDGES; i += stride) {
    int d = dst[i];
    int pos = atomicAdd(&cursor[d], 1);
    srcs[pos] = src[i];
    ((float4*)ea_perm)[pos] = ((const float4*)ea)[i];
  }
}

// ---------------- node encoder h0 = x@Wn + bn; block 0 also folds edge weights
// (wcomb = W_edge@We, bcomb = b_edge@We) -- merged to save a serialized dispatch.
__global__ void k_encode(const float* __restrict__ x, const float* __restrict__ Wn,
                         const float* __restrict__ bn, float* __restrict__ h0,
                         const float* __restrict__ W_edge, const float* __restrict__ b_edge,
                         const float* __restrict__ aWe, const float* __restrict__ cWe,
                         float* __restrict__ wcomb, float* __restrict__ bcomb) {
  __shared__ float lw[8 * ENC];
  __shared__ float lb[ENC];
  int t = threadIdx.x;
  if (blockIdx.x == 0) {  // tiny weight fold (runs alongside block 0's encode share)
    int i = t >> 6, d = t & 63;
    for (int sr = 0; sr < 6; ++sr) {
      const float* We = (sr < 3) ? (aWe + sr * ENC * ENC) : (cWe + (sr - 3) * ENC * ENC);
      float sum = 0.f;
      for (int k = 0; k < ENC; ++k) sum += W_edge[i * ENC + k] * We[k * ENC + d];
      wcomb[sr * 4 * ENC + i * ENC + d] = sum;
      if (t < ENC) {
        float bs = 0.f;
        for (int k = 0; k < ENC; ++k) bs += b_edge[k] * We[k * ENC + t];
        bcomb[sr * ENC + t] = bs;
      }
    }
  }
  for (int i = t; i < 8 * ENC; i += blockDim.x) lw[i] = Wn[i];
  if (t < ENC) lb[t] = bn[t];
  __syncthreads();
  int wid = t >> 6, lane = t & 63;
  int nwaves = (blockDim.x >> 6) * gridDim.x;
  int w = blockIdx.x * (blockDim.x >> 6) + wid;
  for (int n = w; n < N_NODES; n += nwaves) {
    const float4* xr4 = (const float4*)(x + n * 8);
    float4 a = xr4[0], b = xr4[1];
    float acc = lb[lane];
    acc += a.x * lw[0 * ENC + lane] + a.y * lw[1 * ENC + lane] +
           a.z * lw[2 * ENC + lane] + a.w * lw[3 * ENC + lane];
    acc += b.x * lw[4 * ENC + lane] + b.y * lw[5 * ENC + lane] +
           b.z * lw[6 * ENC + lane] + b.w * lw[7 * ENC + lane];
    h0[n * ENC + lane] = acc;
  }
}

// ---------------- per-round double GEMM, both stacks: blockIdx.y = stack -------
__global__ void __launch_bounds__(256) k_gemm2(const float* __restrict__ hinA,
                                               const float* __restrict__ hinC,
                                               const float* __restrict__ WlA,
                                               const float* __restrict__ WrA,
                                               const float* __restrict__ bcA,
                                               float* __restrict__ xlA_,
                                               float* __restrict__ xrA_,
                                               const float* __restrict__ WlC,
                                               const float* __restrict__ WrC,
                                               const float* __restrict__ bcC,
                                               float* __restrict__ xlC_,
                                               float* __restrict__ xrC_) {
  const int stk = blockIdx.y;
  const float* hin = stk ? hinC : hinA;
  const float* Wl = stk ? WlC : WlA;
  const float* Wr = stk ? WrC : WrA;
  const float* bc = stk ? bcC : bcA;
  float* xl = stk ? xlC_ : xlA_;
  float* xr = stk ? xrC_ : xrA_;
  __shared__ float lw[2 * ENC * ENC];  // [mat][k][c]
  __shared__ float lh[64 * ENC];       // [local node][k]
  int t = threadIdx.x;
  {  // stage weights: 2048 float4, fully coalesced
    const float4* wl4 = (const float4*)Wl;
    const float4* wr4 = (const float4*)Wr;
    float4* lw4 = (float4*)lw;
#pragma unroll
    for (int i = 0; i < 4; ++i) lw4[t + 256 * i] = wl4[t + 256 * i];
#pragma unroll
    for (int i = 0; i < 4; ++i) lw4[1024 + t + 256 * i] = wr4[t + 256 * i];
  }
  int base = blockIdx.x * 64;  // first node of tile
  {  // stage h tile: 1024 float4, fully coalesced; clamp OOB to a valid index
    const float4* h4 = (const float4*)hin;
    float4* lh4 = (float4*)lh;
    int maxi = N_NODES * 16 - 1;
#pragma unroll
    for (int i = 0; i < 4; ++i) {
      int idx = t + 256 * i;
      int gi = base * 16 + idx;
      if (gi > maxi) gi = maxi;
      lh4[idx] = h4[gi];
    }
  }
  __syncthreads();
  int wid = t >> 6, lane = t & 63;
  int msel = lane >> 5, cc = lane & 31;
  const float2* lw2 = (const float2*)lw;  // (m,k,cc) at m*2048 + k*32 + cc
  float* outp = msel ? xr : xl;
  float2 bcv = make_float2(0.f, 0.f);
  if (msel) bcv = ((const float2*)bc)[cc];  // fold edge-encoder bias into xr
#pragma unroll
  for (int chunk = 0; chunk < 4; ++chunk) {
    int n0 = wid * 16 + chunk * 4;  // local node of this 4-node chunk
    float a00 = 0.f, a01 = 0.f, a10 = 0.f, a11 = 0.f;
    float a20 = 0.f, a21 = 0.f, a30 = 0.f, a31 = 0.f;
    const float4* r0 = (const float4*)(lh + (n0 + 0) * ENC);
    const float4* r1 = (const float4*)(lh + (n0 + 1) * ENC);
    const float4* r2 = (const float4*)(lh + (n0 + 2) * ENC);
    const float4* r3 = (const float4*)(lh + (n0 + 3) * ENC);
#pragma unroll
    for (int k4 = 0; k4 < 16; ++k4) {
      float4 h0 = r0[k4], h1 = r1[k4], h2 = r2[k4], h3 = r3[k4];
      float2 w0 = lw2[msel * 2048 + (k4 * 4 + 0) * 32 + cc];
      float2 w1 = lw2[msel * 2048 + (k4 * 4 + 1) * 32 + cc];
      float2 w2 = lw2[msel * 2048 + (k4 * 4 + 2) * 32 + cc];
      float2 w3 = lw2[msel * 2048 + (k4 * 4 + 3) * 32 + cc];
      a00 += h0.x * w0.x + h0.y * w1.x + h0.z * w2.x + h0.w * w3.x;
      a01 += h0.x * w0.y + h0.y * w1.y + h0.z * w2.y + h0.w * w3.y;
      a10 += h1.x * w0.x + h1.y * w1.x + h1.z * w2.x + h1.w * w3.x;
      a11 += h1.x * w0.y + h1.y * w1.y + h1.z * w2.y + h1.w * w3.y;
      a20 += h2.x * w0.x + h2.y * w1.x + h2.z * w2.x + h2.w * w3.x;
      a21 += h2.x * w0.y + h2.y * w1.y + h2.z * w2.y + h2.w * w3.y;
      a30 += h3.x * w0.x + h3.y * w1.x + h3.z * w2.x + h3.w * w3.x;
      a31 += h3.x * w0.y + h3.y * w1.y + h3.z * w2.y + h3.w * w3.y;
    }
    int ng = base + n0;
    if (ng + 0 < N_NODES) *(float2*)(outp + (size_t)(ng + 0) * ENC + cc * 2) = make_float2(a00 + bcv.x, a01 + bcv.y);
    if (ng + 1 < N_NODES) *(float2*)(outp + (size_t)(ng + 1) * ENC + cc * 2) = make_float2(a10 + bcv.x, a11 + bcv.y);
    if (ng + 2 < N_NODES) *(float2*)(outp + (size_t)(ng + 2) * ENC + cc * 2) = make_float2(a20 + bcv.x, a21 + bcv.y);
    if (ng + 3 < N_NODES) *(float2*)(outp + (size_t)(ng + 3) * ENC + cc * 2) = make_float2(a30 + bcv.x, a31 + bcv.y);
  }
}

// ---------------- fused score + online softmax + aggregate ------------------
// blockIdx.y selects stack (actor/critic): halves per-wave state/VGPR, doubles
// resident waves for latency hiding. Wave = dst node; 4 groups x 16 lanes, each
// group one edge, float4 channels/lane. Chunk loads (srcs/ea_perm) register-
// double-buffered (prefetch next while computing current); gathers batched
// before scores before online updates (all statically unrolled). Coalesced
// chunk loads + shfl broadcast only - never wave-uniform vector loads
// (round-1 lesson: ~50x fetch amplification).
template <int RELU>
__global__ void __launch_bounds__(256) k_attn(
    const int* __restrict__ row_start, const int* __restrict__ srcs,
    const float* __restrict__ ea_perm,
    const float* __restrict__ xla, const float* __restrict__ xra,
    const float* __restrict__ xlc, const float* __restrict__ xrc,
    const float* __restrict__ wca, const float* __restrict__ wcc,
    const float* __restrict__ atta, const float* __restrict__ attc,
    const float* __restrict__ Ba, const float* __restrict__ Bc,
    float* __restrict__ ha, float* __restrict__ hc) {
  const float NEG_INF = __int_as_float(0xff800000u);
  const int stk = blockIdx.y;
  const float* xl = stk ? xlc : xla;
  const float* xr = stk ? xrc : xra;
  const float* wc = stk ? wcc : wca;
  const float* att = stk ? attc : atta;
  const float* B = stk ? Bc : Ba;
  float* hout = stk ? hc : ha;
  int t = threadIdx.x;
  int wid = t >> 6, lane = t & 63;
  int g = lane >> 4;    // edge slot within wave
  int l16 = lane & 15;  // channel-quad index
  float4 w0 = ((const float4*)(wc + 0 * ENC))[l16];
  float4 w1 = ((const float4*)(wc + 1 * ENC))[l16];
  float4 w2 = ((const float4*)(wc + 2 * ENC))[l16];
  float4 w3 = ((const float4*)(wc + 3 * ENC))[l16];
  float4 at = ((const float4*)att)[l16];
  float4 bv = ((const float4*)B)[l16];
  int nw = (blockDim.x >> 6) * gridDim.x;
  for (int n = blockIdx.x * (blockDim.x >> 6) + wid; n < N_NODES; n += nw) {
    int rs = row_start[n], re = row_start[n + 1];
    float4 outv;
    if (re > rs) {
      float4 xrn = ((const float4*)(xr + (size_t)n * ENC))[l16];
      float m = -1e30f, den = 0.f;
      float4 acc = make_float4(0.f, 0.f, 0.f, 0.f);
      // preload first chunk (register double-buffer)
      int cnt0 = re - rs; if (cnt0 > 16) cnt0 = 16;
      float eav = (lane < 4 * cnt0) ? ea_perm[(size_t)rs * 4 + lane] : 0.f;
      int sval = (lane < cnt0) ? srcs[rs + lane] : 0;
      for (int base = rs; base < re; base += 16) {
        int cnt = re - base; if (cnt > 16) cnt = 16;
        float eav_c = eav;
        int sval_c = sval;
        int nb = base + 16;
        if (nb < re) {  // wave-uniform prefetch of next chunk
          int cn = re - nb; if (cn > 16) cn = 16;
          eav = (lane < 4 * cn) ? ea_perm[(size_t)nb * 4 + lane] : 0.f;
          sval = (lane < cn) ? srcs[nb + lane] : 0;
        }
        // ---- batch gather (independent, statically unrolled) ----
        float4 la[4];
        bool act[4];
#pragma unroll
        for (int j = 0; j < 4; ++j) {
          int jj = j * 4 + g;
          act[j] = jj < cnt;
          int sj = __shfl(sval_c, act[j] ? jj : (cnt - 1));
          la[j] = ((const float4*)xl)[sj * 16 + l16];
        }
        // ---- scores ----
        float px[4];
#pragma unroll
        for (int j = 0; j < 4; ++j) {
          int jj = j * 4 + g;
          float av0 = __shfl(eav_c, jj * 4 + 0);
          float av1 = __shfl(eav_c, jj * 4 + 1);
          float av2 = __shfl(eav_c, jj * 4 + 2);
          float av3 = __shfl(eav_c, jj * 4 + 3);
          float p = lrelu(la[j].x + xrn.x + av0 * w0.x + av1 * w1.x + av2 * w2.x + av3 * w3.x) * at.x;
          p += lrelu(la[j].y + xrn.y + av0 * w0.y + av1 * w1.y + av2 * w2.y + av3 * w3.y) * at.y;
          p += lrelu(la[j].z + xrn.z + av0 * w0.z + av1 * w1.z + av2 * w2.z + av3 * w3.z) * at.z;
          p += lrelu(la[j].w + xrn.w + av0 * w0.w + av1 * w1.w + av2 * w2.w + av3 * w3.w) * at.w;
          p += __shfl_xor(p, 1);
          p += __shfl_xor(p, 2);
          p += __shfl_xor(p, 4);
          p += __shfl_xor(p, 8);
          px[j] = act[j] ? p : NEG_INF;
        }
        // ---- online softmax updates (per-group chain) ----
#pragma unroll
        for (int j = 0; j < 4; ++j) {
          float mn = fmaxf(m, px[j]);
          float sc = __expf(m - mn);
          float ex = __expf(px[j] - mn);
          den = den * sc + ex;
          acc.x = acc.x * sc + ex * la[j].x;
          acc.y = acc.y * sc + ex * la[j].y;
          acc.z = acc.z * sc + ex * la[j].z;
          acc.w = acc.w * sc + ex * la[j].w;
          m = mn;
        }
      }
      // merge the 4 group-states (butterfly over lane distance 16, 32)
#pragma unroll
      for (int d = 16; d <= 32; d <<= 1) {
        float m2 = __shfl_xor(m, d);
        float dn2 = __shfl_xor(den, d);
        float a2x = __shfl_xor(acc.x, d), a2y = __shfl_xor(acc.y, d);
        float a2z = __shfl_xor(acc.z, d), a2w = __shfl_xor(acc.w, d);
        float mn = fmaxf(m, m2);
        float s1 = __expf(m - mn), s2 = __expf(m2 - mn);
        den = den * s1 + dn2 * s2;
        acc.x = acc.x * s1 + a2x * s2;
        acc.y = acc.y * s1 + a2y * s2;
        acc.z = acc.z * s1 + a2z * s2;
        acc.w = acc.w * s1 + a2w * s2;
        m = mn;
      }
      float inv = 1.f / den;
      outv = make_float4(acc.x * inv + bv.x, acc.y * inv + bv.y,
                         acc.z * inv + bv.z, acc.w * inv + bv.w);
    } else {
      outv = bv;
    }
    if (RELU) {
      outv.x = fmaxf(outv.x, 0.f);
      outv.y = fmaxf(outv.y, 0.f);
      outv.z = fmaxf(outv.z, 0.f);
      outv.w = fmaxf(outv.w, 0.f);
    }
    if (g == 0) ((float4*)(hout + (size_t)n * ENC))[l16] = outv;
  }
}

// ---------------- fused decoders ----------------
__global__ void k_dec(const float* __restrict__ ha, const float* __restrict__ hc,
                      const float* __restrict__ Wa, const float* __restrict__ ba,
                      const float* __restrict__ Wv, const float* __restrict__ bv,
                      float* __restrict__ out) {
  int t = threadIdx.x;
  int wid = t >> 6, lane = t & 63;
  int nw = (blockDim.x >> 6) * gridDim.x;
  int w = blockIdx.x * (blockDim.x >> 6) + wid;
  for (int n = w; n < N_NODES; n += nw) {
    float hva = ha[(size_t)n * ENC + lane];
    float hvc = hc[(size_t)n * ENC + lane];
#pragma unroll
    for (int j = 0; j < 5; ++j) {
      float p = hva * Wa[lane * 5 + j];
      p += __shfl_xor(p, 1);
      p += __shfl_xor(p, 2);
      p += __shfl_xor(p, 4);
      p += __shfl_xor(p, 8);
      p += __shfl_xor(p, 16);
      p += __shfl_xor(p, 32);
      if (lane == 0) out[n * 6 + j] = tanhf(p + ba[j]);
    }
    float p = hvc * Wv[lane];
    p += __shfl_xor(p, 1);
    p += __shfl_xor(p, 2);
    p += __shfl_xor(p, 4);
    p += __shfl_xor(p, 8);
    p += __shfl_xor(p, 16);
    p += __shfl_xor(p, 32);
    if (lane == 0) out[n * 6 + 5] = p + bv[0];
  }
}

extern "C" void kernel_launch(void* const* d_in, const int* in_sizes, int n_in,
                              void* d_out, int out_size, void* d_ws, size_t ws_size,
                              hipStream_t stream) {
  const float* x    = (const float*)d_in[0];
  const float* ea   = (const float*)d_in[1];
  const float* Wn   = (const float*)d_in[2];
  const float* bn   = (const float*)d_in[3];
  const float* Wedg = (const float*)d_in[4];
  const float* bedg = (const float*)d_in[5];
  const float* aWl  = (const float*)d_in[6];
  const float* aWr  = (const float*)d_in[7];
  const float* aWe  = (const float*)d_in[8];
  const float* aAtt = (const float*)d_in[9];
  const float* aB   = (const float*)d_in[10];
  const float* cWl  = (const float*)d_in[11];
  const float* cWr  = (const float*)d_in[12];
  const float* cWe  = (const float*)d_in[13];
  const float* cAtt = (const float*)d_in[14];
  const float* cB   = (const float*)d_in[15];
  const float* Wa   = (const float*)d_in[16];
  const float* ba   = (const float*)d_in[17];
  const float* Wv   = (const float*)d_in[18];
  const float* bv   = (const float*)d_in[19];
  const int* src    = (const int*)d_in[20];
  const int* dst    = (const int*)d_in[21];
  float* out = (float*)d_out;

  char* w = (char*)d_ws;
  size_t off = 0;
  auto alloc = [&](size_t bytes) -> char* {
    char* p = w + off;
    off = (off + bytes + 255) & ~(size_t)255;
    return p;
  };
  float* h0  = (float*)alloc((size_t)N_NODES * ENC * 4);
  float* hA  = (float*)alloc((size_t)N_NODES * ENC * 4);
  float* hC  = (float*)alloc((size_t)N_NODES * ENC * 4);
  float* xlA = (float*)alloc((size_t)N_NODES * ENC * 4);
  float* xrA = (float*)alloc((size_t)N_NODES * ENC * 4);
  float* xlC = (float*)alloc((size_t)N_NODES * ENC * 4);
  float* xrC = (float*)alloc((size_t)N_NODES * ENC * 4);
  int* srcs      = (int*)alloc((size_t)N_EDGES * 4);
  float* ea_perm = (float*)alloc((size_t)N_EDGES * 16);
  int* row_start = (int*)alloc((size_t)(N_NODES + 1) * 4);
  int* cursor    = (int*)alloc((size_t)N_NODES * 4);
  int* part      = (int*)alloc(256 * 4);
  float* wcomb   = (float*)alloc(6 * 4 * ENC * 4);
  float* bcomb   = (float*)alloc(6 * ENC * 4);

  // ---- CSR build ----
  hipMemsetAsync(cursor, 0, (size_t)N_NODES * 4, stream);
  k_hist<<<2048, 256, 0, stream>>>(dst, cursor);
  k_red<<<SCAN_BLOCKS, 256, 0, stream>>>(cursor, part);
  k_scanp<<<1, 256, 0, stream>>>(part);
  k_csr<<<SCAN_BLOCKS, 256, 0, stream>>>(cursor, part, row_start);
  k_scatter<<<2048, 256, 0, stream>>>(src, dst, ea, cursor, srcs, ea_perm);

  // ---- encoder (+ folded edge weights in block 0) ----
  k_encode<<<512, 256, 0, stream>>>(x, Wn, bn, h0, Wedg, bedg, aWe, cWe, wcomb, bcomb);

  const int GEMM_TILES = (N_NODES + 63) / 64;  // 782

  for (int r = 0; r < ROUNDS; ++r) {
    const float* hinA = (r == 0) ? h0 : hA;
    const float* hinC = (r == 0) ? h0 : hC;
    k_gemm2<<<dim3(GEMM_TILES, 2), 256, 0, stream>>>(
        hinA, hinC, aWl + r * ENC * ENC, aWr + r * ENC * ENC, bcomb + r * ENC, xlA, xrA,
        cWl + r * ENC * ENC, cWr + r * ENC * ENC, bcomb + (3 + r) * ENC, xlC, xrC);
    if (r < ROUNDS - 1)
      k_attn<1><<<dim3(2048, 2), 256, 0, stream>>>(row_start, srcs, ea_perm, xlA, xrA, xlC, xrC,
                                                   wcomb + r * 4 * ENC, wcomb + (3 + r) * 4 * ENC,
                                                   aAtt + r * ENC, cAtt + r * ENC,
                                                   aB + r * ENC, cB + r * ENC, hA, hC);
    else
      k_attn<0><<<dim3(2048, 2), 256, 0, stream>>>(row_start, srcs, ea_perm, xlA, xrA, xlC, xrC,
                                                   wcomb + r * 4 * ENC, wcomb + (3 + r) * 4 * ENC,
                                                   aAtt + r * ENC, cAtt + r * ENC,
                                                   aB + r * ENC, cB + r * ENC, hA, hC);
  }
  k_dec<<<1024, 256, 0, stream>>>(hA, hC, Wa, ba, Wv, bv, out);
}

// Round 6
// 689.837 us; speedup vs baseline: 1.2258x; 1.2258x over previous
//
#include <hip/hip_runtime.h>
#include <math.h>

#define N_NODES 50000
#define N_EDGES 800000
#define ENC 64
#define ROUNDS 3
#define NEG_SLOPE 0.2f

typedef unsigned int u32;

__device__ __forceinline__ float lrelu(float m) {
  return m > 0.f ? m : NEG_SLOPE * m;
}

// ---------------- CSR build ----------------
__global__ void k_hist(const int* __restrict__ dst, int* __restrict__ deg) {
  int i = blockIdx.x * blockDim.x + threadIdx.x;
  int stride = gridDim.x * blockDim.x;
  for (; i < N_EDGES; i += stride) atomicAdd(&deg[dst[i]], 1);
}

#define SCAN_BLOCKS ((N_NODES + 255) / 256)  // 196

__global__ void __launch_bounds__(256) k_red(const int* __restrict__ deg,
                                             int* __restrict__ part) {
  __shared__ int sm[256];
  int bi = blockIdx.x, t = threadIdx.x;
  int i = bi * 256 + t;
  sm[t] = (i < N_NODES) ? deg[i] : 0;
  __syncthreads();
  for (int off = 128; off > 0; off >>= 1) {
    if (t < off) sm[t] += sm[t + off];
    __syncthreads();
  }
  if (t == 0) part[bi] = sm[0];
}

__global__ void __launch_bounds__(256) k_scanp(int* __restrict__ part) {
  __shared__ int sm[256];
  int t = threadIdx.x;
  int v = (t < SCAN_BLOCKS) ? part[t] : 0;
  sm[t] = v;
  __syncthreads();
  for (int off = 1; off < 256; off <<= 1) {
    int u = (t >= off) ? sm[t - off] : 0;
    __syncthreads();
    sm[t] += u;
    __syncthreads();
  }
  if (t < SCAN_BLOCKS) part[t] = sm[t] - v;  // exclusive
}

// degcur: degrees on entry, scatter cursors (= row_start) on exit.
__global__ void __launch_bounds__(256) k_csr(int* __restrict__ degcur,
                                             const int* __restrict__ part,
                                             int* __restrict__ row_start) {
  __shared__ int sm[256];
  int bi = blockIdx.x, t = threadIdx.x;
  int i = bi * 256 + t;
  int v = (i < N_NODES) ? degcur[i] : 0;
  sm[t] = v;
  __syncthreads();
  for (int off = 1; off < 256; off <<= 1) {
    int u = (t >= off) ? sm[t - off] : 0;
    __syncthreads();
    sm[t] += u;
    __syncthreads();
  }
  int excl = sm[t] - v + part[bi];
  if (i < N_NODES) {
    row_start[i] = excl;
    degcur[i] = excl;
    if (i == N_NODES - 1) row_start[N_NODES] = excl + v;
  }
}

// scatter edges into CSR order; also permute edge_attr so the fused kernel
// reads it coalesced (ea_perm[pos] = ea[e]).
__global__ void k_scatter(const int* __restrict__ src, const int* __restrict__ dst,
                          const float* __restrict__ ea, int* __restrict__ cursor,
                          int* __restrict__ srcs, float* __restrict__ ea_perm) {
  int i = blockIdx.x * blockDim.x + threadIdx.x;
  int stride = gridDim.x * blockDim.x;
  for (; i < N_EDGES; i += stride) {
    int d = dst[i];
    int pos = atomicAdd(&cursor[d], 1);
    srcs[pos] = src[i];
    ((float4*)ea_perm)[pos] = ((const float4*)ea)[i];
  }
}

// ---------------- node encoder h0 = x@Wn + bn; block 0 also folds edge weights
// (wcomb = W_edge@We, bcomb = b_edge@We) -- merged to save a serialized dispatch.
__global__ void k_encode(const float* __restrict__ x, const float* __restrict__ Wn,
                         const float* __restrict__ bn, float* __restrict__ h0,
                         const float* __restrict__ W_edge, const float* __restrict__ b_edge,
                         const float* __restrict__ aWe, const float* __restrict__ cWe,
                         float* __restrict__ wcomb, float* __restrict__ bcomb) {
  __shared__ float lw[8 * ENC];
  __shared__ float lb[ENC];
  int t = threadIdx.x;
  if (blockIdx.x == 0) {  // tiny weight fold (runs alongside block 0's encode share)
    int i = t >> 6, d = t & 63;
    for (int sr = 0; sr < 6; ++sr) {
      const float* We = (sr < 3) ? (aWe + sr * ENC * ENC) : (cWe + (sr - 3) * ENC * ENC);
      float sum = 0.f;
      for (int k = 0; k < ENC; ++k) sum += W_edge[i * ENC + k] * We[k * ENC + d];
      wcomb[sr * 4 * ENC + i * ENC + d] = sum;
      if (t < ENC) {
        float bs = 0.f;
        for (int k = 0; k < ENC; ++k) bs += b_edge[k] * We[k * ENC + t];
        bcomb[sr * ENC + t] = bs;
      }
    }
  }
  for (int i = t; i < 8 * ENC; i += blockDim.x) lw[i] = Wn[i];
  if (t < ENC) lb[t] = bn[t];
  __syncthreads();
  int wid = t >> 6, lane = t & 63;
  int nwaves = (blockDim.x >> 6) * gridDim.x;
  int w = blockIdx.x * (blockDim.x >> 6) + wid;
  for (int n = w; n < N_NODES; n += nwaves) {
    const float4* xr4 = (const float4*)(x + n * 8);
    float4 a = xr4[0], b = xr4[1];
    float acc = lb[lane];
    acc += a.x * lw[0 * ENC + lane] + a.y * lw[1 * ENC + lane] +
           a.z * lw[2 * ENC + lane] + a.w * lw[3 * ENC + lane];
    acc += b.x * lw[4 * ENC + lane] + b.y * lw[5 * ENC + lane] +
           b.z * lw[6 * ENC + lane] + b.w * lw[7 * ENC + lane];
    h0[n * ENC + lane] = acc;
  }
}

// ---------------- per-round double GEMM, both stacks: blockIdx.y = stack.
// Writes xl/xr into STACK-INTERLEAVED layout [n][stack][64] so the attention
// kernel gathers one contiguous 512B row per edge covering both stacks. -------
__global__ void __launch_bounds__(256) k_gemm2(const float* __restrict__ hinA,
                                               const float* __restrict__ hinC,
                                               const float* __restrict__ WlA,
                                               const float* __restrict__ WrA,
                                               const float* __restrict__ bcA,
                                               const float* __restrict__ WlC,
                                               const float* __restrict__ WrC,
                                               const float* __restrict__ bcC,
                                               float* __restrict__ xl_comb,
                                               float* __restrict__ xr_comb) {
  const int stk = blockIdx.y;
  const float* hin = stk ? hinC : hinA;
  const float* Wl = stk ? WlC : WlA;
  const float* Wr = stk ? WrC : WrA;
  const float* bc = stk ? bcC : bcA;
  __shared__ float lw[2 * ENC * ENC];  // [mat][k][c]
  __shared__ float lh[64 * ENC];       // [local node][k]
  int t = threadIdx.x;
  {  // stage weights: 2048 float4, fully coalesced
    const float4* wl4 = (const float4*)Wl;
    const float4* wr4 = (const float4*)Wr;
    float4* lw4 = (float4*)lw;
#pragma unroll
    for (int i = 0; i < 4; ++i) lw4[t + 256 * i] = wl4[t + 256 * i];
#pragma unroll
    for (int i = 0; i < 4; ++i) lw4[1024 + t + 256 * i] = wr4[t + 256 * i];
  }
  int base = blockIdx.x * 64;  // first node of tile
  {  // stage h tile: 1024 float4, fully coalesced; clamp OOB to a valid index
    const float4* h4 = (const float4*)hin;
    float4* lh4 = (float4*)lh;
    int maxi = N_NODES * 16 - 1;
#pragma unroll
    for (int i = 0; i < 4; ++i) {
      int idx = t + 256 * i;
      int gi = base * 16 + idx;
      if (gi > maxi) gi = maxi;
      lh4[idx] = h4[gi];
    }
  }
  __syncthreads();
  int wid = t >> 6, lane = t & 63;
  int msel = lane >> 5, cc = lane & 31;
  const float2* lw2 = (const float2*)lw;  // (m,k,cc) at m*2048 + k*32 + cc
  float* outp = (msel ? xr_comb : xl_comb) + stk * 64;  // interleaved row offset
  float2 bcv = make_float2(0.f, 0.f);
  if (msel) bcv = ((const float2*)bc)[cc];  // fold edge-encoder bias into xr
#pragma unroll
  for (int chunk = 0; chunk < 4; ++chunk) {
    int n0 = wid * 16 + chunk * 4;  // local node of this 4-node chunk
    float a00 = 0.f, a01 = 0.f, a10 = 0.f, a11 = 0.f;
    float a20 = 0.f, a21 = 0.f, a30 = 0.f, a31 = 0.f;
    const float4* r0 = (const float4*)(lh + (n0 + 0) * ENC);
    const float4* r1 = (const float4*)(lh + (n0 + 1) * ENC);
    const float4* r2 = (const float4*)(lh + (n0 + 2) * ENC);
    const float4* r3 = (const float4*)(lh + (n0 + 3) * ENC);
#pragma unroll
    for (int k4 = 0; k4 < 16; ++k4) {
      float4 h0 = r0[k4], h1 = r1[k4], h2 = r2[k4], h3 = r3[k4];
      float2 w0 = lw2[msel * 2048 + (k4 * 4 + 0) * 32 + cc];
      float2 w1 = lw2[msel * 2048 + (k4 * 4 + 1) * 32 + cc];
      float2 w2 = lw2[msel * 2048 + (k4 * 4 + 2) * 32 + cc];
      float2 w3 = lw2[msel * 2048 + (k4 * 4 + 3) * 32 + cc];
      a00 += h0.x * w0.x + h0.y * w1.x + h0.z * w2.x + h0.w * w3.x;
      a01 += h0.x * w0.y + h0.y * w1.y + h0.z * w2.y + h0.w * w3.y;
      a10 += h1.x * w0.x + h1.y * w1.x + h1.z * w2.x + h1.w * w3.x;
      a11 += h1.x * w0.y + h1.y * w1.y + h1.z * w2.y + h1.w * w3.y;
      a20 += h2.x * w0.x + h2.y * w1.x + h2.z * w2.x + h2.w * w3.x;
      a21 += h2.x * w0.y + h2.y * w1.y + h2.z * w2.y + h2.w * w3.y;
      a30 += h3.x * w0.x + h3.y * w1.x + h3.z * w2.x + h3.w * w3.x;
      a31 += h3.x * w0.y + h3.y * w1.y + h3.z * w2.y + h3.w * w3.y;
    }
    int ng = base + n0;
    if (ng + 0 < N_NODES) *(float2*)(outp + (size_t)(ng + 0) * 128 + cc * 2) = make_float2(a00 + bcv.x, a01 + bcv.y);
    if (ng + 1 < N_NODES) *(float2*)(outp + (size_t)(ng + 1) * 128 + cc * 2) = make_float2(a10 + bcv.x, a11 + bcv.y);
    if (ng + 2 < N_NODES) *(float2*)(outp + (size_t)(ng + 2) * 128 + cc * 2) = make_float2(a20 + bcv.x, a21 + bcv.y);
    if (ng + 3 < N_NODES) *(float2*)(outp + (size_t)(ng + 3) * 128 + cc * 2) = make_float2(a30 + bcv.x, a31 + bcv.y);
  }
}

// ---------------- fused score + online softmax + aggregate ------------------
// Wave = dst node. Lane = {edge-slot g2(2)} x {stack sl(2)} x {channel-quad
// l16(16)}: each 32-lane half processes one edge; lanes 0-15 of the half do the
// actor stack, 16-31 the critic. ONE register set (weights/att/bias/state) per
// lane, stack-selected via per-lane base pointers -> half the VGPR of the
// round-4 version while chunk loads + shfl broadcasts are still shared by both
// stacks (round-5 lesson: never duplicate shared chunk work across waves).
// xl/xr are stack-interleaved [n][2][64]: one contiguous 512B gather per edge.
// Chunk loads (srcs/ea_perm) register-double-buffered; edge pairs 2-deep
// unrolled for gather ILP. Coalesced chunk loads + shfl broadcast only -
// never wave-uniform vector loads (round-1 lesson: ~50x amplification).
template <int RELU>
__global__ void __launch_bounds__(256) k_attn(
    const int* __restrict__ row_start, const int* __restrict__ srcs,
    const float* __restrict__ ea_perm,
    const float* __restrict__ xl_comb, const float* __restrict__ xr_comb,
    const float* __restrict__ wca, const float* __restrict__ wcc,
    const float* __restrict__ atta, const float* __restrict__ attc,
    const float* __restrict__ Ba, const float* __restrict__ Bc,
    float* __restrict__ ha, float* __restrict__ hc) {
  const float NEG_INF = __int_as_float(0xff800000u);
  int t = threadIdx.x;
  int wid = t >> 6, lane = t & 63;
  int g2 = lane >> 5;        // edge slot within wave
  int sl = (lane >> 4) & 1;  // stack (0=actor, 1=critic)
  int l16 = lane & 15;       // channel-quad index
  int q32 = lane & 31;       // quad index within interleaved 128-float row
  const float* wcS = sl ? wcc : wca;
  const float* attS = sl ? attc : atta;
  const float* BS = sl ? Bc : Ba;
  float* houtS = sl ? hc : ha;
  float4 w0 = ((const float4*)(wcS + 0 * ENC))[l16];
  float4 w1 = ((const float4*)(wcS + 1 * ENC))[l16];
  float4 w2 = ((const float4*)(wcS + 2 * ENC))[l16];
  float4 w3 = ((const float4*)(wcS + 3 * ENC))[l16];
  float4 at = ((const float4*)attS)[l16];
  float4 bv = ((const float4*)BS)[l16];
  int nw = (blockDim.x >> 6) * gridDim.x;
  for (int n = blockIdx.x * (blockDim.x >> 6) + wid; n < N_NODES; n += nw) {
    int rs = row_start[n], re = row_start[n + 1];
    float4 outv;
    if (re > rs) {
      float4 xrn = ((const float4*)xr_comb)[(size_t)n * 32 + q32];
      float m = -1e30f, den = 0.f;
      float4 acc = make_float4(0.f, 0.f, 0.f, 0.f);
      // preload first chunk (register double-buffer)
      int cnt0 = re - rs; if (cnt0 > 16) cnt0 = 16;
      float eav = (lane < 4 * cnt0) ? ea_perm[(size_t)rs * 4 + lane] : 0.f;
      int sval = (lane < cnt0) ? srcs[rs + lane] : 0;
      for (int base = rs; base < re; base += 16) {
        int cnt = re - base; if (cnt > 16) cnt = 16;
        float eav_c = eav;
        int sval_c = sval;
        int nb = base + 16;
        if (nb < re) {  // wave-uniform prefetch of next chunk
          int cn = re - nb; if (cn > 16) cn = 16;
          eav = (lane < 4 * cn) ? ea_perm[(size_t)nb * 4 + lane] : 0.f;
          sval = (lane < cn) ? srcs[nb + lane] : 0;
        }
        // 16 edges = 4 pair-iterations x (2 edge slots x 2-deep unroll)
        for (int jp = 0; jp < 4; ++jp) {
          if (jp * 4 >= cnt) break;  // wave-uniform
          int jjA = jp * 4 + g2;
          int jjB = jjA + 2;
          bool actA = jjA < cnt, actB = jjB < cnt;
          int snA = __shfl(sval_c, actA ? jjA : 0);
          int snB = __shfl(sval_c, actB ? jjB : 0);
          // both gathers issued before use (ILP)
          float4 laA = ((const float4*)xl_comb)[(size_t)snA * 32 + q32];
          float4 laB = ((const float4*)xl_comb)[(size_t)snB * 32 + q32];
          float aA0 = __shfl(eav_c, jjA * 4 + 0);
          float aA1 = __shfl(eav_c, jjA * 4 + 1);
          float aA2 = __shfl(eav_c, jjA * 4 + 2);
          float aA3 = __shfl(eav_c, jjA * 4 + 3);
          float aB0 = __shfl(eav_c, jjB * 4 + 0);
          float aB1 = __shfl(eav_c, jjB * 4 + 1);
          float aB2 = __shfl(eav_c, jjB * 4 + 2);
          float aB3 = __shfl(eav_c, jjB * 4 + 3);
          // scores (4 channels/lane, one stack/lane), reduce within 16 lanes
          float pA = lrelu(laA.x + xrn.x + aA0 * w0.x + aA1 * w1.x + aA2 * w2.x + aA3 * w3.x) * at.x;
          pA += lrelu(laA.y + xrn.y + aA0 * w0.y + aA1 * w1.y + aA2 * w2.y + aA3 * w3.y) * at.y;
          pA += lrelu(laA.z + xrn.z + aA0 * w0.z + aA1 * w1.z + aA2 * w2.z + aA3 * w3.z) * at.z;
          pA += lrelu(laA.w + xrn.w + aA0 * w0.w + aA1 * w1.w + aA2 * w2.w + aA3 * w3.w) * at.w;
          float pB = lrelu(laB.x + xrn.x + aB0 * w0.x + aB1 * w1.x + aB2 * w2.x + aB3 * w3.x) * at.x;
          pB += lrelu(laB.y + xrn.y + aB0 * w0.y + aB1 * w1.y + aB2 * w2.y + aB3 * w3.y) * at.y;
          pB += lrelu(laB.z + xrn.z + aB0 * w0.z + aB1 * w1.z + aB2 * w2.z + aB3 * w3.z) * at.z;
          pB += lrelu(laB.w + xrn.w + aB0 * w0.w + aB1 * w1.w + aB2 * w2.w + aB3 * w3.w) * at.w;
          pA += __shfl_xor(pA, 1); pB += __shfl_xor(pB, 1);
          pA += __shfl_xor(pA, 2); pB += __shfl_xor(pB, 2);
          pA += __shfl_xor(pA, 4); pB += __shfl_xor(pB, 4);
          pA += __shfl_xor(pA, 8); pB += __shfl_xor(pB, 8);
          pA = actA ? pA : NEG_INF;
          pB = actB ? pB : NEG_INF;
          // two serial online-softmax updates (each serves 2 edges x 2 stacks)
          {
            float mn = fmaxf(m, pA);
            float sc = __expf(m - mn);
            float ex = __expf(pA - mn);
            den = den * sc + ex;
            acc.x = acc.x * sc + ex * laA.x;
            acc.y = acc.y * sc + ex * laA.y;
            acc.z = acc.z * sc + ex * laA.z;
            acc.w = acc.w * sc + ex * laA.w;
            m = mn;
          }
          {
            float mn = fmaxf(m, pB);
            float sc = __expf(m - mn);
            float ex = __expf(pB - mn);
            den = den * sc + ex;
            acc.x = acc.x * sc + ex * laB.x;
            acc.y = acc.y * sc + ex * laB.y;
            acc.z = acc.z * sc + ex * laB.z;
            acc.w = acc.w * sc + ex * laB.w;
            m = mn;
          }
        }
      }
      // merge the 2 edge-slot states (xor 32; stacks stay in their lanes)
      {
        float m2 = __shfl_xor(m, 32);
        float dn2 = __shfl_xor(den, 32);
        float a2x = __shfl_xor(acc.x, 32), a2y = __shfl_xor(acc.y, 32);
        float a2z = __shfl_xor(acc.z, 32), a2w = __shfl_xor(acc.w, 32);
        float mn = fmaxf(m, m2);
        float s1 = __expf(m - mn), s2 = __expf(m2 - mn);
        den = den * s1 + dn2 * s2;
        acc.x = acc.x * s1 + a2x * s2;
        acc.y = acc.y * s1 + a2y * s2;
        acc.z = acc.z * s1 + a2z * s2;
        acc.w = acc.w * s1 + a2w * s2;
      }
      float inv = 1.f / den;
      outv = make_float4(acc.x * inv + bv.x, acc.y * inv + bv.y,
                         acc.z * inv + bv.z, acc.w * inv + bv.w);
    } else {
      outv = bv;
    }
    if (RELU) {
      outv.x = fmaxf(outv.x, 0.f);
      outv.y = fmaxf(outv.y, 0.f);
      outv.z = fmaxf(outv.z, 0.f);
      outv.w = fmaxf(outv.w, 0.f);
    }
    if (g2 == 0) ((float4*)houtS)[(size_t)n * 16 + l16] = outv;
  }
}

// ---------------- fused decoders ----------------
__global__ void k_dec(const float* __restrict__ ha, const float* __restrict__ hc,
                      const float* __restrict__ Wa, const float* __restrict__ ba,
                      const float* __restrict__ Wv, const float* __restrict__ bv,
                      float* __restrict__ out) {
  int t = threadIdx.x;
  int wid = t >> 6, lane = t & 63;
  int nw = (blockDim.x >> 6) * gridDim.x;
  int w = blockIdx.x * (blockDim.x >> 6) + wid;
  for (int n = w; n < N_NODES; n += nw) {
    float hva = ha[(size_t)n * ENC + lane];
    float hvc = hc[(size_t)n * ENC + lane];
#pragma unroll
    for (int j = 0; j < 5; ++j) {
      float p = hva * Wa[lane * 5 + j];
      p += __shfl_xor(p, 1);
      p += __shfl_xor(p, 2);
      p += __shfl_xor(p, 4);
      p += __shfl_xor(p, 8);
      p += __shfl_xor(p, 16);
      p += __shfl_xor(p, 32);
      if (lane == 0) out[n * 6 + j] = tanhf(p + ba[j]);
    }
    float p = hvc * Wv[lane];
    p += __shfl_xor(p, 1);
    p += __shfl_xor(p, 2);
    p += __shfl_xor(p, 4);
    p += __shfl_xor(p, 8);
    p += __shfl_xor(p, 16);
    p += __shfl_xor(p, 32);
    if (lane == 0) out[n * 6 + 5] = p + bv[0];
  }
}

extern "C" void kernel_launch(void* const* d_in, const int* in_sizes, int n_in,
                              void* d_out, int out_size, void* d_ws, size_t ws_size,
                              hipStream_t stream) {
  const float* x    = (const float*)d_in[0];
  const float* ea   = (const float*)d_in[1];
  const float* Wn   = (const float*)d_in[2];
  const float* bn   = (const float*)d_in[3];
  const float* Wedg = (const float*)d_in[4];
  const float* bedg = (const float*)d_in[5];
  const float* aWl  = (const float*)d_in[6];
  const float* aWr  = (const float*)d_in[7];
  const float* aWe  = (const float*)d_in[8];
  const float* aAtt = (const float*)d_in[9];
  const float* aB   = (const float*)d_in[10];
  const float* cWl  = (const float*)d_in[11];
  const float* cWr  = (const float*)d_in[12];
  const float* cWe  = (const float*)d_in[13];
  const float* cAtt = (const float*)d_in[14];
  const float* cB   = (const float*)d_in[15];
  const float* Wa   = (const float*)d_in[16];
  const float* ba   = (const float*)d_in[17];
  const float* Wv   = (const float*)d_in[18];
  const float* bv   = (const float*)d_in[19];
  const int* src    = (const int*)d_in[20];
  const int* dst    = (const int*)d_in[21];
  float* out = (float*)d_out;

  char* w = (char*)d_ws;
  size_t off = 0;
  auto alloc = [&](size_t bytes) -> char* {
    char* p = w + off;
    off = (off + bytes + 255) & ~(size_t)255;
    return p;
  };
  float* h0  = (float*)alloc((size_t)N_NODES * ENC * 4);
  float* hA  = (float*)alloc((size_t)N_NODES * ENC * 4);
  float* hC  = (float*)alloc((size_t)N_NODES * ENC * 4);
  float* xl_comb = (float*)alloc((size_t)N_NODES * 2 * ENC * 4);  // [n][stack][64]
  float* xr_comb = (float*)alloc((size_t)N_NODES * 2 * ENC * 4);  // [n][stack][64]
  int* srcs      = (int*)alloc((size_t)N_EDGES * 4);
  float* ea_perm = (float*)alloc((size_t)N_EDGES * 16);
  int* row_start = (int*)alloc((size_t)(N_NODES + 1) * 4);
  int* cursor    = (int*)alloc((size_t)N_NODES * 4);
  int* part      = (int*)alloc(256 * 4);
  float* wcomb   = (float*)alloc(6 * 4 * ENC * 4);
  float* bcomb   = (float*)alloc(6 * ENC * 4);

  // ---- CSR build ----
  hipMemsetAsync(cursor, 0, (size_t)N_NODES * 4, stream);
  k_hist<<<2048, 256, 0, stream>>>(dst, cursor);
  k_red<<<SCAN_BLOCKS, 256, 0, stream>>>(cursor, part);
  k_scanp<<<1, 256, 0, stream>>>(part);
  k_csr<<<SCAN_BLOCKS, 256, 0, stream>>>(cursor, part, row_start);
  k_scatter<<<2048, 256, 0, stream>>>(src, dst, ea, cursor, srcs, ea_perm);

  // ---- encoder (+ folded edge weights in block 0) ----
  k_encode<<<512, 256, 0, stream>>>(x, Wn, bn, h0, Wedg, bedg, aWe, cWe, wcomb, bcomb);

  const int GEMM_TILES = (N_NODES + 63) / 64;  // 782

  for (int r = 0; r < ROUNDS; ++r) {
    const float* hinA = (r == 0) ? h0 : hA;
    const float* hinC = (r == 0) ? h0 : hC;
    k_gemm2<<<dim3(GEMM_TILES, 2), 256, 0, stream>>>(
        hinA, hinC, aWl + r * ENC * ENC, aWr + r * ENC * ENC, bcomb + r * ENC,
        cWl + r * ENC * ENC, cWr + r * ENC * ENC, bcomb + (3 + r) * ENC,
        xl_comb, xr_comb);
    if (r < ROUNDS - 1)
      k_attn<1><<<2048, 256, 0, stream>>>(row_start, srcs, ea_perm, xl_comb, xr_comb,
                                          wcomb + r * 4 * ENC, wcomb + (3 + r) * 4 * ENC,
                                          aAtt + r * ENC, cAtt + r * ENC,
                                          aB + r * ENC, cB + r * ENC, hA, hC);
    else
      k_attn<0><<<2048, 256, 0, stream>>>(row_start, srcs, ea_perm, xl_comb, xr_comb,
                                          wcomb + r * 4 * ENC, wcomb + (3 + r) * 4 * ENC,
                                          aAtt + r * ENC, cAtt + r * ENC,
                                          aB + r * ENC, cB + r * ENC, hA, hC);
  }
  k_dec<<<1024, 256, 0, stream>>>(hA, hC, Wa, ba, Wv, bv, out);
}